// Round 6
// baseline (50.224 us; speedup 1.0000x reference)
//
#include <hip/hip_runtime.h>
#include <math.h>

// ParametricEQ: 5-section cascaded biquad over (32, 131072).
// Single 10-state linear recurrence z' = A z + b x, two launches:
//   K1 setup: RBJ coeffs (fp64) + P_m = A^(32*2^m) m=0..11; zero publish flags.
//   K2 main (512 blocks x 256 thr; block = 256 chunks x 32 samples):
//     x staged COALESCED into padded LDS (stride 33, conflict-free chunk reads);
//     P matrices -> LDS; zero-state cascade (LDS-fed) -> chunk states;
//     in-wave KS (P_0..P_5); block aggregate via P_6; publish (agent release);
//     wait 16 sibling flags; in-wave KS over aggregates (P_8..P_11);
//     per-thread reconstruction; final cascade -> y in LDS -> coalesced out.

#define NB 32
#define LCH 32
#define T_LEN 131072
#define CPB 256                 // chunks per block
#define SPB 16                  // blocks (spans) per batch
#define NPOW 12
#define PROW 12                 // padded row stride (floats) for LDS P
#define XSTR 33                 // padded chunk stride in LDS (floats)

__constant__ double c_lo[15] = {-12.0,   20.0, 0.1,
                                -12.0,   20.0, 0.1,
                                -12.0,  200.0, 0.1,
                                -12.0, 2000.0, 0.1,
                                -12.0, 4000.0, 0.1};
__constant__ double c_hi[15] = { 12.0,  2000.0, 10.0,
                                 12.0,   200.0, 10.0,
                                 12.0,  2000.0, 10.0,
                                 12.0, 12000.0, 10.0,
                                 12.0, 16000.0, 10.0};

// ---------------- K1: coeffs + cascade matrix powers + flag clear -----------
__global__ __launch_bounds__(128)
void eq_setup(const float* __restrict__ cp, float* __restrict__ sos_out,
              float* __restrict__ powers, unsigned int* __restrict__ flags)
{
    int b = blockIdx.x;
    int t = threadIdx.x;
    __shared__ float  sc[5][5];
    __shared__ double Abuf[2][10][10];

    if (t < SPB) flags[b * SPB + t] = 0u;   // clear publish flags (pre-main)

    if (t < 5) {
        int k = t;
        double p[3];
#pragma unroll
        for (int j = 0; j < 3; ++j) {
            int i = k * 3 + j;
            double pv = (double)cp[b * 15 + i];
            p[j] = c_lo[i] + pv * (c_hi[i] - c_lo[i]);
        }
        double A     = exp(p[0] * (M_LN10 / 40.0));
        double w0    = 2.0 * M_PI * p[1] / 44100.0;
        double alpha = sin(w0) / (2.0 * p[2]);
        double cw    = cos(w0);
        double sA    = sqrt(A);
        double b0, b1, b2, a0, a1, a2;
        if (k == 0) {            // low shelf
            b0 =     A * ((A + 1) - (A - 1) * cw + 2 * sA * alpha);
            b1 = 2 * A * ((A - 1) - (A + 1) * cw);
            b2 =     A * ((A + 1) - (A - 1) * cw - 2 * sA * alpha);
            a0 =          (A + 1) + (A - 1) * cw + 2 * sA * alpha;
            a1 =    -2 * ((A - 1) + (A + 1) * cw);
            a2 =          (A + 1) + (A - 1) * cw - 2 * sA * alpha;
        } else if (k == 4) {     // high shelf
            b0 =     A * ((A + 1) + (A - 1) * cw + 2 * sA * alpha);
            b1 = -2 * A * ((A - 1) + (A + 1) * cw);
            b2 =     A * ((A + 1) + (A - 1) * cw - 2 * sA * alpha);
            a0 =          (A + 1) - (A - 1) * cw + 2 * sA * alpha;
            a1 =     2 * ((A - 1) - (A + 1) * cw);
            a2 =          (A + 1) - (A - 1) * cw - 2 * sA * alpha;
        } else {                 // peaking
            b0 = 1.0 + alpha * A;
            b1 = -2.0 * cw;
            b2 = 1.0 - alpha * A;
            a0 = 1.0 + alpha / A;
            a1 = -2.0 * cw;
            a2 = 1.0 - alpha / A;
        }
        double inv = 1.0 / a0;
        float fb0 = (float)(b0 * inv), fb1 = (float)(b1 * inv), fb2 = (float)(b2 * inv);
        float fa1 = (float)(a1 * inv), fa2 = (float)(a2 * inv);
        float* o = sos_out + (size_t)(b * 5 + k) * 6;
        o[0] = fb0; o[1] = fb1; o[2] = fb2; o[3] = 1.0f; o[4] = fa1; o[5] = fa2;
        sc[k][0] = fb0; sc[k][1] = fb1; sc[k][2] = fb2; sc[k][3] = fa1; sc[k][4] = fa2;
    }
    __syncthreads();

    // A (10x10): column i = one-sample cascade update of basis e_i with x=0.
    if (t < 10) {
        double z[10];
#pragma unroll
        for (int i = 0; i < 10; ++i) z[i] = 0.0;
        z[t] = 1.0;
        double s = 0.0;
        double zn[10];
#pragma unroll
        for (int k = 0; k < 5; ++k) {
            double b0 = sc[k][0], b1 = sc[k][1], b2 = sc[k][2];
            double a1 = sc[k][3], a2 = sc[k][4];
            double y = b0 * s + z[2 * k];
            zn[2 * k]     = b1 * s - a1 * y + z[2 * k + 1];
            zn[2 * k + 1] = b2 * s - a2 * y;
            s = y;
        }
#pragma unroll
        for (int r = 0; r < 10; ++r) Abuf[0][r][t] = zn[r];
    }
    __syncthreads();

    int r = t / 10, cc = t % 10;
    int cur = 0;
    for (int sq = 0; sq < 16; ++sq) {
        double acc = 0.0;
        if (t < 100) {
#pragma unroll
            for (int j = 0; j < 10; ++j) acc += Abuf[cur][r][j] * Abuf[cur][j][cc];
        }
        __syncthreads();
        if (t < 100) Abuf[cur ^ 1][r][cc] = acc;
        __syncthreads();
        cur ^= 1;
        if (sq >= 4 && t < 100) {
            int m = sq - 4;   // sq=4 -> A^32 = P_0
            powers[((size_t)b * NPOW + m) * 100 + t] = (float)Abuf[cur][r][cc];
        }
    }
}

// ---- v = P*u (+ v if ACC), P = LDS 10x12 padded rows, u[10..11]==0 ----------
template<bool ACC>
__device__ __forceinline__ void affineL(const float* __restrict__ P,
                                        const float u[PROW], float v[10])
{
#pragma unroll
    for (int rr = 0; rr < 10; ++rr) {
        const float* rp = P + rr * PROW;
        float a = ACC ? v[rr] : 0.0f;
#pragma unroll
        for (int c = 0; c < PROW; ++c) a = fmaf(rp[c], u[c], a);
        v[rr] = a;
    }
}

__device__ __forceinline__ void matvecL(const float* __restrict__ P, float v[10])
{
    float u[PROW];
#pragma unroll
    for (int i = 0; i < 10; ++i) u[i] = v[i];
    u[10] = 0.0f; u[11] = 0.0f;
    affineL<false>(P, u, v);
}

// ---------------- K2: main ----------------
__global__ __launch_bounds__(256, 2)
void eq_main(const float* __restrict__ x, const float* __restrict__ sos,
             const float* __restrict__ powers, float* __restrict__ agg,
             unsigned int* __restrict__ flags, float* __restrict__ y)
{
    int blk = blockIdx.x;
    int b = blk >> 4, sp = blk & (SPB - 1);
    int tid = threadIdx.x;
    int w = tid >> 6, lw = tid & 63;

    __shared__ float Pl[NPOW * 10 * PROW];   // P matrices, padded (5.76 KB)
    __shared__ float xs_[CPB * XSTR];        // signal, padded stride 33 (33 KB)
    __shared__ float wt[4][10];
    __shared__ float Sseed[10];

    // ---- stage x coalesced into padded LDS ----
    const float* xg = x + (size_t)b * T_LEN + (size_t)sp * (CPB * LCH);
#pragma unroll
    for (int it = 0; it < (CPB * LCH) / (256 * 4); ++it) {
        int i = (tid + it * 256) * 4;
        float4 v = *reinterpret_cast<const float4*>(xg + i);
        int p = i + (i >> 5);                // sample -> padded index
        xs_[p] = v.x; xs_[p + 1] = v.y; xs_[p + 2] = v.z; xs_[p + 3] = v.w;
    }

    // ---- stage P matrices into LDS (pad cols 10,11 with 0) ----
    {
        const float* src = powers + (size_t)b * NPOW * 100;
        for (int i = tid; i < NPOW * 10 * PROW; i += 256) {
            int c = i % PROW;
            int r = (i / PROW) % 10;
            int m = i / (10 * PROW);
            Pl[i] = (c < 10) ? src[m * 100 + r * 10 + c] : 0.0f;
        }
    }

    const float* s5 = sos + (size_t)(b * 5) * 6;
    float cb0[5], cb1[5], cb2[5], ca1[5], ca2[5];
#pragma unroll
    for (int k = 0; k < 5; ++k) {
        cb0[k] = s5[k * 6 + 0]; cb1[k] = s5[k * 6 + 1]; cb2[k] = s5[k * 6 + 2];
        ca1[k] = s5[k * 6 + 4]; ca2[k] = s5[k * 6 + 5];
    }

    __syncthreads();   // xs_, Pl staged

    // ---- zero-state cascade (LDS-fed) -> chunk end state ----
    float* xc = xs_ + tid * XSTR;            // this thread's chunk (bank (tid+j)%32)
    float z1[5] = {0, 0, 0, 0, 0}, z2[5] = {0, 0, 0, 0, 0};
#pragma unroll
    for (int j = 0; j < LCH; ++j) {
        float s = xc[j];
#pragma unroll
        for (int k = 0; k < 5; ++k) {
            float yk = fmaf(cb0[k], s, z1[k]);
            float u  = fmaf(cb1[k], s, z2[k]);
            z1[k] = fmaf(-ca1[k], yk, u);
            z2[k] = fmaf(-ca2[k], yk, cb2[k] * s);
            s = yk;
        }
    }
    float sv[10];
#pragma unroll
    for (int k = 0; k < 5; ++k) { sv[2 * k] = z1[k]; sv[2 * k + 1] = z2[k]; }

    // ---- in-wave KS scan over 64 chunks (P_0..P_5 from LDS) ----
#pragma unroll
    for (int j = 0; j < 6; ++j) {
        const float* P = Pl + j * 10 * PROW;
        float u[PROW];
#pragma unroll
        for (int i = 0; i < 10; ++i) u[i] = __shfl_up(sv[i], 1 << j);
        u[10] = 0.0f; u[11] = 0.0f;
        if (lw >= (1 << j)) affineL<true>(P, u, sv);
    }
    // exclusive in-wave prefix
    float es[10];
#pragma unroll
    for (int i = 0; i < 10; ++i) es[i] = __shfl_up(sv[i], 1);
    if (lw == 0) {
#pragma unroll
        for (int i = 0; i < 10; ++i) es[i] = 0.0f;
    }
    if (lw == 63) {
#pragma unroll
        for (int i = 0; i < 10; ++i) wt[w][i] = sv[i];
    }
    __syncthreads();

    // ---- block aggregate (thread 0): E = P6*E + wt[j], publish ----
    if (tid == 0) {
        float E[10];
#pragma unroll
        for (int i = 0; i < 10; ++i) E[i] = wt[0][i];
#pragma unroll
        for (int j = 1; j < 4; ++j) {
            matvecL(Pl + 6 * 10 * PROW, E);
#pragma unroll
            for (int i = 0; i < 10; ++i) E[i] += wt[j][i];
        }
        float* ap = agg + (size_t)(b * SPB + sp) * 10;
#pragma unroll
        for (int i = 0; i < 10; ++i)
            __hip_atomic_store(&ap[i], E[i], __ATOMIC_RELAXED, __HIP_MEMORY_SCOPE_AGENT);
        __hip_atomic_store(&flags[b * SPB + sp], 1u, __ATOMIC_RELEASE,
                           __HIP_MEMORY_SCOPE_AGENT);
    }

    // ---- wave 0: wait 16 sibling aggregates, KS over 16 (P_8..P_11) ----
    if (w == 0) {
        float tv[10];
#pragma unroll
        for (int i = 0; i < 10; ++i) tv[i] = 0.0f;
        if (lw < SPB) {
            while (__hip_atomic_load(&flags[b * SPB + lw], __ATOMIC_ACQUIRE,
                                     __HIP_MEMORY_SCOPE_AGENT) == 0u) {
                __builtin_amdgcn_s_sleep(1);
            }
            const float* ap = agg + (size_t)(b * SPB + lw) * 10;
#pragma unroll
            for (int i = 0; i < 10; ++i)
                tv[i] = __hip_atomic_load(&ap[i], __ATOMIC_RELAXED,
                                          __HIP_MEMORY_SCOPE_AGENT);
        }
#pragma unroll
        for (int j = 0; j < 4; ++j) {
            const float* P = Pl + (8 + j) * 10 * PROW;
            float u[PROW];
#pragma unroll
            for (int i = 0; i < 10; ++i) u[i] = __shfl_up(tv[i], 1 << j);
            u[10] = 0.0f; u[11] = 0.0f;
            if (lw >= (1 << j) && lw < SPB) affineL<true>(P, u, tv);
        }
        float sd[10];
#pragma unroll
        for (int i = 0; i < 10; ++i) sd[i] = __shfl(tv[i], (sp - 1) & 63);
        if (sp == 0) {
#pragma unroll
            for (int i = 0; i < 10; ++i) sd[i] = 0.0f;
        }
        if (lw == 0) {
#pragma unroll
            for (int i = 0; i < 10; ++i) Sseed[i] = sd[i];
        }
    }
    __syncthreads();

    // ---- exact entering state for this chunk ----
    float F[10];
#pragma unroll
    for (int i = 0; i < 10; ++i) F[i] = Sseed[i];
    if (w & 1) matvecL(Pl + 6 * 10 * PROW, F);   // A^2048
    if (w & 2) matvecL(Pl + 7 * 10 * PROW, F);   // A^4096
    {
        float Ew[10];
#pragma unroll
        for (int i = 0; i < 10; ++i) Ew[i] = 0.0f;
        for (int j = 0; j < w; ++j) {
            matvecL(Pl + 6 * 10 * PROW, Ew);
#pragma unroll
            for (int i = 0; i < 10; ++i) Ew[i] += wt[j][i];
        }
#pragma unroll
        for (int i = 0; i < 10; ++i) F[i] += Ew[i];
    }
#pragma unroll
    for (int m = 0; m < 6; ++m) {
        if ((lw >> m) & 1) matvecL(Pl + m * 10 * PROW, F);
    }
#pragma unroll
    for (int k = 0; k < 5; ++k) {
        z1[k] = F[2 * k]     + es[2 * k];
        z2[k] = F[2 * k + 1] + es[2 * k + 1];
    }

    // ---- final cascade from exact state -> y (in place in LDS) ----
#pragma unroll
    for (int j = 0; j < LCH; ++j) {
        float s = xc[j];
#pragma unroll
        for (int k = 0; k < 5; ++k) {
            float yk = fmaf(cb0[k], s, z1[k]);
            float u  = fmaf(cb1[k], s, z2[k]);
            z1[k] = fmaf(-ca1[k], yk, u);
            z2[k] = fmaf(-ca2[k], yk, cb2[k] * s);
            s = yk;
        }
        xc[j] = s;
    }
    __syncthreads();

    // ---- coalesced copy-out ----
    float* yg = y + (size_t)b * T_LEN + (size_t)sp * (CPB * LCH);
#pragma unroll
    for (int it = 0; it < (CPB * LCH) / (256 * 4); ++it) {
        int i = (tid + it * 256) * 4;
        int p = i + (i >> 5);
        *reinterpret_cast<float4*>(yg + i) =
            make_float4(xs_[p], xs_[p + 1], xs_[p + 2], xs_[p + 3]);
    }
}

extern "C" void kernel_launch(void* const* d_in, const int* in_sizes, int n_in,
                              void* d_out, int out_size, void* d_ws, size_t ws_size,
                              hipStream_t stream)
{
    const float* x  = (const float*)d_in[0];
    const float* cp = (const float*)d_in[1];
    float* out = (float*)d_out;
    float* sos = out + (size_t)NB * T_LEN;                 // sos tail of d_out

    float*        powers = (float*)d_ws;                   // NB*NPOW*100
    float*        agg    = powers + (size_t)NB * NPOW * 100;   // NB*16*10
    unsigned int* flags  = (unsigned int*)(agg + (size_t)NB * SPB * 10);  // NB*16

    eq_setup<<<dim3(NB), dim3(128), 0, stream>>>(cp, sos, powers, flags);
    eq_main<<<dim3(NB * SPB), dim3(256), 0, stream>>>(x, sos, powers, agg, flags, out);
}